// Round 3
// baseline (1282.002 us; speedup 1.0000x reference)
//
#include <hip/hip_runtime.h>
#include <math.h>

// ---------------- problem constants ----------------
#define NN 10000          // nodes
#define NE 320000         // edges
#define NGR 16            // graphs
#define NGROUPS16 (NE/16) // 20000 edge groups of 16

// workspace offsets (bytes) -- all 16B aligned
#define OFF_BLOB  0u          // 108 frags * 1KB bf16 weight blob
#define OFF_SLIN  110592u     // N*64 bf16
#define OFF_VLIN  1390592u    // N*96 bf16 (layout [n][d*32+w])
#define OFF_ACCS  3310592u    // N*64 f32 (segment sum zs)
#define OFF_ACCV  5870592u    // N*96 f32 (segment sum zv, layout [n][d*32+w])
#define OFF_GRP   9710592u    // 64 f32 group accumulators (contiguous w/ acc for 1 memset)
#define OFF_NS    9710848u    // N*64 f32 scratch
#define OFF_NV    12270848u   // N*96 f32 scratch

typedef __attribute__((ext_vector_type(8))) short s8v;   // 8 bf16 = one MFMA A/B frag
typedef __attribute__((ext_vector_type(4))) float f4v;   // MFMA C/D frag

__device__ __forceinline__ short f2bf(float f) {
  union { float f; unsigned u; } v; v.f = f;
  unsigned r = v.u + 0x7fffu + ((v.u >> 16) & 1u);
  return (short)(r >> 16);
}
__device__ __forceinline__ float bf2f(short s) {
  union { float f; unsigned u; } v; v.u = ((unsigned)(unsigned short)s) << 16;
  return v.f;
}
__device__ __forceinline__ f4v mfma16(s8v a, s8v b, f4v c) {
  return __builtin_amdgcn_mfma_f32_16x16x32_bf16(a, b, c, 0, 0, 0);
}
__device__ __forceinline__ s8v ldB(const short* blob, int f, int lane) {
  return *(const s8v*)(blob + f*512 + lane*8);
}
__device__ __forceinline__ s8v cvt8v(f4v a, f4v b) {
  s8v r;
  r[0]=f2bf(a[0]); r[1]=f2bf(a[1]); r[2]=f2bf(a[2]); r[3]=f2bf(a[3]);
  r[4]=f2bf(b[0]); r[5]=f2bf(b[1]); r[6]=f2bf(b[2]); r[7]=f2bf(b[3]);
  return r;
}
__device__ __forceinline__ float wave_sum(float v) {
  #pragma unroll
  for (int off = 32; off > 0; off >>= 1) v += __shfl_xor(v, off);
  return v;
}

// ---------------- K0: pack weights into bf16 B-fragment blob ----------------
// frag layout: B[k=q*8+j][n=lane&15] for tile (kt,nt); frag ids:
//  P1  [Wss0|Wssg|Wsv1] 192x128 : f = nt*6+kt        (nt<8,kt<6)  -> 0..47   (x 1/fan)
//  P2  [Wvv0|Wvvg]      96x96   : f = 48+nt*3+kt     (nt<6,kt<3)  -> 48..65  (x 1/fan)
//  P3  Wvs1             96x32   : f = 66+nt*3+kt     (nt<2,kt<3)  -> 66..71  (x 1/fan)
//  FC1 128x64           : f = 72+nt*4+kt             (nt<4,kt<4)  -> 72..87
//  FC2 64x64            : f = 88+nt*2+kt             (nt<4,kt<2)  -> 88..95
//  FC3 64x96            : f = 96+nt*2+kt             (nt<6,kt<2)  -> 96..107
__global__ void k_prep(const float* W_ss0, const float* W_ssg, const float* W_sv1,
                       const float* W_vv0, const float* W_vvg, const float* W_vs1,
                       const float* fc_W1, const float* fc_W2, const float* fc_W3,
                       short* blob) {
  const float inv_fan = 0.05892556509887896f; // 1/sqrt(288)
  int f = blockIdx.x, l = threadIdx.x;
  int q = l >> 4, nl = l & 15;
  s8v out;
  #pragma unroll
  for (int j = 0; j < 8; ++j) {
    float w;
    if (f < 48) {
      int nt = f / 6, kt = f % 6, k = kt*32 + q*8 + j, c = nt*16 + nl;
      w = (c < 64 ? W_ss0[k*64 + c] : (c < 96 ? W_ssg[k*32 + (c-64)] : W_sv1[k*32 + (c-96)])) * inv_fan;
    } else if (f < 66) {
      int fl = f - 48, nt = fl / 3, kt = fl % 3, k = kt*32 + q*8 + j, c = nt*16 + nl;
      w = (c < 64 ? W_vv0[k*64 + c] : W_vvg[k*32 + (c-64)]) * inv_fan;
    } else if (f < 72) {
      int fl = f - 66, nt = fl / 3, kt = fl % 3, k = kt*32 + q*8 + j, c = nt*16 + nl;
      w = W_vs1[k*32 + c] * inv_fan;
    } else if (f < 88) {
      int fl = f - 72, nt = fl / 4, kt = fl % 4, k = kt*32 + q*8 + j, c = nt*16 + nl;
      w = fc_W1[k*64 + c];
    } else if (f < 96) {
      int fl = f - 88, nt = fl / 2, kt = fl % 2, k = kt*32 + q*8 + j, c = nt*16 + nl;
      w = fc_W2[k*64 + c];
    } else {
      int fl = f - 96, nt = fl / 2, kt = fl % 2, k = kt*32 + q*8 + j, c = nt*16 + nl;
      w = fc_W3[k*96 + c];
    }
    out[j] = f2bf(w);
  }
  *(s8v*)(blob + f*512 + l*8) = out;
}

// ---------------- K1: per-node linear pre-transform (lp), store bf16 ----------------
__global__ void k_node(const float* node_fea, const float* lp_Ws, const float* lp_bs,
                       const float* lp_Wv, short* s_lin, short* v_linT) {
  int n = blockIdx.x, lane = threadIdx.x;
  const float* nf = node_fea + n*160;
  float a = 0.f;
  for (int u = 0; u < 64; ++u) a += nf[u] * lp_Ws[u*64 + lane];
  s_lin[n*64 + lane] = f2bf(a * 0.125f + lp_bs[lane]);
  for (int o = lane; o < 96; o += 64) {
    int d = o >> 5, w = o & 31;
    float acc = 0.f;
    for (int u = 0; u < 32; ++u) acc += nf[64 + u*3 + d] * lp_Wv[u*32 + w];
    v_linT[n*96 + o] = f2bf(acc * 0.17677669529663687f); // 1/sqrt(32)
  }
}

// ---------------- K2: edge kernel (MFMA) ----------------
// one wave per 16-edge group; batch-issued loads, compute in issue order.
// 512-thread blocks, __launch_bounds__(512,4): VGPR cap 128 (== measured use,
// no spill) with 2 co-resident blocks/CU -> 16 waves/CU (2x round-2 occupancy).
__launch_bounds__(512, 4)
__global__ void k_edge(const float* edge_sh, const float* edge_fea, const float* ele,
                       const int* eidx, const short* blob,
                       const short* s_lin, const short* v_linT,
                       const float* fc_b1, const float* fc_b2, const float* fc_b3,
                       float* acc_s, float* acc_v) {
  __shared__ __align__(16) short hbuf[8][1024];  // per-wave 16x64 bf16 transpose buffer
  int lane = threadIdx.x & 63, wave = threadIdx.x >> 6;
  int q = lane >> 4, nl = lane & 15;
  short* hb = hbuf[wave];
  // hoist biases (constant over groups)
  float b1v[4], b2v[4], b3v[6];
  #pragma unroll
  for (int t = 0; t < 4; ++t) { b1v[t] = fc_b1[t*16 + nl]; b2v[t] = fc_b2[t*16 + nl]; }
  #pragma unroll
  for (int t = 0; t < 6; ++t) b3v[t] = fc_b3[t*16 + nl];

  int nwaves = gridDim.x * 8;
  for (int g = blockIdx.x*8 + wave; g < NGROUPS16; g += nwaves) {
    int base = g * 16;
    int eA = base + nl;
    // ======== BATCH 1: independent loads (streams + indices) ========
    int iA = eidx[eA], jA = eidx[NE + eA];
    f4v shE = *(const f4v*)(edge_sh + eA*4);
    const float* efp = edge_fea + eA*160;
    f4v es0 = *(const f4v*)(efp + q*8);
    f4v es1 = *(const f4v*)(efp + q*8 + 4);
    f4v es2 = *(const f4v*)(efp + 32 + q*8);
    f4v es3 = *(const f4v*)(efp + 32 + q*8 + 4);
    f4v ev[6];
    #pragma unroll
    for (int t = 0; t < 6; ++t) ev[t] = *(const f4v*)(efp + 64 + q*24 + t*4);
    f4v el[8];
    #pragma unroll
    for (int kt = 0; kt < 4; ++kt) {
      el[2*kt]   = *(const f4v*)(ele + eA*128 + kt*32 + q*8);
      el[2*kt+1] = *(const f4v*)(ele + eA*128 + kt*32 + q*8 + 4);
    }
    // ======== BATCH 2: eidx-dependent gathers (already bf16) ========
    s8v a_s1[6];
    a_s1[0] = *(const s8v*)(s_lin + iA*64 + q*8);
    a_s1[1] = *(const s8v*)(s_lin + iA*64 + 32 + q*8);
    a_s1[2] = *(const s8v*)(s_lin + jA*64 + q*8);
    a_s1[3] = *(const s8v*)(s_lin + jA*64 + 32 + q*8);
    s8v a_v[3][3];
    #pragma unroll
    for (int d = 0; d < 3; ++d) {
      a_v[d][0] = *(const s8v*)(v_linT + iA*96 + d*32 + q*8);
      a_v[d][1] = *(const s8v*)(v_linT + jA*96 + d*32 + q*8);
    }

    // ======== COMPUTE (consume in issue order; gathers consumed last) ========
    // ---- FC chain first (consumes ele stream)
    s8v a_e[4];
    #pragma unroll
    for (int kt = 0; kt < 4; ++kt) a_e[kt] = cvt8v(el[2*kt], el[2*kt+1]);
    #pragma unroll
    for (int nt = 0; nt < 4; ++nt) {
      f4v acc = {0.f, 0.f, 0.f, 0.f};
      #pragma unroll
      for (int kt = 0; kt < 4; ++kt) acc = mfma16(a_e[kt], ldB(blob, 72 + nt*4 + kt, lane), acc);
      #pragma unroll
      for (int r = 0; r < 4; ++r) {
        float x = acc[r] + b1v[nt];
        x = x / (1.f + __expf(-x));
        hb[(q*4 + r)*64 + nt*16 + nl] = f2bf(x);
      }
    }
    s8v ha0 = *(const s8v*)(hb + nl*64 + q*8);
    s8v ha1 = *(const s8v*)(hb + nl*64 + 32 + q*8);
    #pragma unroll
    for (int nt = 0; nt < 4; ++nt) {
      f4v acc = {0.f, 0.f, 0.f, 0.f};
      acc = mfma16(ha0, ldB(blob, 88 + nt*2 + 0, lane), acc);
      acc = mfma16(ha1, ldB(blob, 88 + nt*2 + 1, lane), acc);
      #pragma unroll
      for (int r = 0; r < 4; ++r) {
        float x = acc[r] + b2v[nt];
        x = x / (1.f + __expf(-x));
        hb[(q*4 + r)*64 + nt*16 + nl] = f2bf(x);
      }
    }
    s8v g0 = *(const s8v*)(hb + nl*64 + q*8);
    s8v g1 = *(const s8v*)(hb + nl*64 + 32 + q*8);
    f4v Wfc[6];
    #pragma unroll
    for (int nt = 0; nt < 6; ++nt) {
      f4v acc = {0.f, 0.f, 0.f, 0.f};
      acc = mfma16(g0, ldB(blob, 96 + nt*2 + 0, lane), acc);
      acc = mfma16(g1, ldB(blob, 96 + nt*2 + 1, lane), acc);
      #pragma unroll
      for (int r = 0; r < 4; ++r) acc[r] += b3v[nt];
      Wfc[nt] = acc;
    }
    // ---- convert es / ev tails (consumes edge_fea stream)
    a_s1[4] = cvt8v(es0, es1);
    a_s1[5] = cvt8v(es2, es3);
    #pragma unroll
    for (int d = 0; d < 3; ++d)
      #pragma unroll
      for (int j = 0; j < 8; ++j) {
        int idx = j*3 + d;
        a_v[d][2][j] = f2bf(ev[idx >> 2][idx & 3]);
      }
    // ---- dd = sum_d v1_d * sh1_d / sqrt(3)
    float s10 = shE[1] * 0.5773502691896258f;
    float s11 = shE[2] * 0.5773502691896258f;
    float s12 = shE[3] * 0.5773502691896258f;
    s8v a_dd[3];
    #pragma unroll
    for (int kt = 0; kt < 3; ++kt)
      #pragma unroll
      for (int j = 0; j < 8; ++j)
        a_dd[kt][j] = f2bf(bf2f(a_v[0][kt][j])*s10 + bf2f(a_v[1][kt][j])*s11 + bf2f(a_v[2][kt][j])*s12);
    // ---- P2 = dd @ [Wvv0|Wvvg]/fan        (16x96)
    f4v P2[6];
    #pragma unroll
    for (int nt = 0; nt < 6; ++nt) {
      f4v acc = {0.f, 0.f, 0.f, 0.f};
      #pragma unroll
      for (int kt = 0; kt < 3; ++kt) acc = mfma16(a_dd[kt], ldB(blob, 48 + nt*3 + kt, lane), acc);
      P2[nt] = acc;
    }
    // ---- P3_d = v1_d @ Wvs1/fan           (16x32 per dim, B reused across dims)
    f4v P3[3][2];
    #pragma unroll
    for (int d = 0; d < 3; ++d)
      #pragma unroll
      for (int nt = 0; nt < 2; ++nt) P3[d][nt] = (f4v){0.f, 0.f, 0.f, 0.f};
    #pragma unroll
    for (int nt = 0; nt < 2; ++nt)
      #pragma unroll
      for (int kt = 0; kt < 3; ++kt) {
        s8v b = ldB(blob, 66 + nt*3 + kt, lane);
        #pragma unroll
        for (int d = 0; d < 3; ++d) P3[d][nt] = mfma16(a_v[d][kt], b, P3[d][nt]);
      }
    // ---- epilogue per-edge scalars via intra-wave shuffle (lanes 0..15 own them)
    int nodeI[4]; float sh0v[4], sh1v[4][3];
    #pragma unroll
    for (int r = 0; r < 4; ++r) {
      int src = q*4 + r;
      nodeI[r] = __shfl(iA, src);
      sh0v[r] = __shfl(shE[0], src);
      sh1v[r][0] = __shfl(shE[1], src);
      sh1v[r][1] = __shfl(shE[2], src);
      sh1v[r][2] = __shfl(shE[3], src);
    }
    // ---- P1 tiles computed on demand, fused with epilogue (never all 8 live)
    // zs tiles nt=0..3
    #pragma unroll
    for (int nt = 0; nt < 4; ++nt) {
      f4v acc = {0.f, 0.f, 0.f, 0.f};
      #pragma unroll
      for (int kt = 0; kt < 6; ++kt) acc = mfma16(a_s1[kt], ldB(blob, nt*6 + kt, lane), acc);
      #pragma unroll
      for (int r = 0; r < 4; ++r) {
        float zs = acc[r] * sh0v[r] + P2[nt][r];
        zs = zs / (1.f + __expf(-zs)) * Wfc[nt][r];
        unsafeAtomicAdd(acc_s + nodeI[r]*64 + nt*16 + nl, zs);
      }
    }
    // zv tiles: gate (nt=4+tg) and sv (nt=6+tg) computed per tg
    #pragma unroll
    for (int tg = 0; tg < 2; ++tg) {
      f4v accg = {0.f, 0.f, 0.f, 0.f};
      f4v accv = {0.f, 0.f, 0.f, 0.f};
      #pragma unroll
      for (int kt = 0; kt < 6; ++kt) {
        accg = mfma16(a_s1[kt], ldB(blob, (4+tg)*6 + kt, lane), accg);
        accv = mfma16(a_s1[kt], ldB(blob, (6+tg)*6 + kt, lane), accv);
      }
      #pragma unroll
      for (int r = 0; r < 4; ++r) {
        float zg = accg[r] * sh0v[r] + P2[4+tg][r];
        float gw = Wfc[4+tg][r] / (1.f + __expf(-zg));  // sigmoid(zg) * w[64+w]
        float sv = accv[r];
        #pragma unroll
        for (int d = 0; d < 3; ++d) {
          float zv = sv * sh1v[r][d] + P3[d][tg][r] * sh0v[r];
          // acc_v layout [n][d*32+w]: one atomic instr touches 16*4B contiguous
          unsafeAtomicAdd(acc_v + nodeI[r]*96 + d*32 + tg*16 + nl, zv * gw);
        }
      }
    }
  }
}

// ---------------- K3: per-node pp-transform + sc, group stats (single pass) ----------------
// variance folded in via E[x^2] - mu^2 -> no second stats pass needed.
__global__ void k_post1(const float* node_fea, const float* one_hot, const int* batch,
                        const float* pp_Ws, const float* pp_bs, const float* pp_Wv,
                        const float* sc_Ws, const float* sc_Wv,
                        const float* acc_s, const float* acc_v,
                        float* ns_buf, float* nv_buf, float* grp) {
  int n = blockIdx.x, lane = threadIdx.x, g = batch[n];
  const float* oh = one_hot + n*4;
  int sp = oh[1] > 0.5f ? 1 : (oh[2] > 0.5f ? 2 : (oh[3] > 0.5f ? 3 : 0));
  const float* nf = node_fea + n*160;
  float a = 0.f, sc = 0.f;
  for (int u = 0; u < 64; ++u) {
    a  += acc_s[n*64 + u] * pp_Ws[u*64 + lane];
    sc += nf[u] * sc_Ws[(u*4 + sp)*64 + lane];
  }
  float ns = a * 0.125f + pp_bs[lane] + sc * 0.0625f;  // /8, /16
  ns_buf[n*64 + lane] = ns;
  float ssum = wave_sum(ns);
  float s2sum = wave_sum(ns * ns);
  float v2 = 0.f;
  for (int o = lane; o < 96; o += 64) {
    int w = o / 3, i = o - w*3;
    float av = 0.f, scv = 0.f;
    for (int u = 0; u < 32; ++u) {
      av  += acc_v[n*96 + i*32 + u] * pp_Wv[u*32 + w];   // acc_v layout [n][d*32+u]
      scv += nf[64 + u*3 + i] * sc_Wv[(u*4 + sp)*32 + w];
    }
    float nv = av * 0.17677669529663687f + scv * 0.08838834764831844f; // /sqrt32, /sqrt128
    nv_buf[n*96 + o] = nv;
    v2 += nv * nv;
  }
  float vsum = wave_sum(v2);
  if (lane == 0) {
    unsafeAtomicAdd(grp + g, ssum * (1.f/64.f));
    unsafeAtomicAdd(grp + 16 + g, 1.f);
    unsafeAtomicAdd(grp + 32 + g, vsum * (1.f/96.f));
    unsafeAtomicAdd(grp + 48 + g, s2sum * (1.f/64.f));
  }
}

// ---------------- K5: center + normalize + residual + output ----------------
__global__ void k_post3(const float* node_fea, const int* batch,
                        const float* ln_w_s, const float* ln_b_s, const float* ln_w_v,
                        const float* ns_buf, const float* nv_buf, const float* grp,
                        float* out) {
  int n = blockIdx.x, lane = threadIdx.x, g = batch[n];
  float cnt = fmaxf(grp[16 + g], 1.f);
  float mu = grp[g] / cnt;
  float var_s = fmaxf(grp[48 + g] / cnt - mu*mu, 0.f);
  float inv_s = rsqrtf(var_s + 1e-5f);
  float inv_v = rsqrtf(grp[32 + g] / cnt + 1e-5f);
  const float* nf = node_fea + n*160;
  out[n*160 + lane] = nf[lane] + (ns_buf[n*64 + lane] - mu) * inv_s * ln_w_s[lane] + ln_b_s[lane];
  for (int o = lane; o < 96; o += 64) {
    int w = o / 3;
    out[n*160 + 64 + o] = nf[64 + o] + nv_buf[n*96 + o] * inv_v * ln_w_v[w];
  }
}

extern "C" void kernel_launch(void* const* d_in, const int* in_sizes, int n_in,
                              void* d_out, int out_size, void* d_ws, size_t ws_size,
                              hipStream_t stream) {
  const float* node_fea = (const float*)d_in[0];
  const float* one_hot  = (const float*)d_in[1];
  const float* edge_sh  = (const float*)d_in[2];
  const float* edge_fea = (const float*)d_in[3];
  const float* ele      = (const float*)d_in[4];
  const int*   eidx     = (const int*)d_in[5];
  const int*   batch    = (const int*)d_in[6];
  const float* lp_Ws = (const float*)d_in[7];
  const float* lp_bs = (const float*)d_in[8];
  const float* lp_Wv = (const float*)d_in[9];
  const float* pp_Ws = (const float*)d_in[10];
  const float* pp_bs = (const float*)d_in[11];
  const float* pp_Wv = (const float*)d_in[12];
  const float* sc_Ws = (const float*)d_in[13];
  const float* sc_Wv = (const float*)d_in[14];
  const float* W_ss0 = (const float*)d_in[15];
  const float* W_vv0 = (const float*)d_in[16];
  const float* W_ssg = (const float*)d_in[17];
  const float* W_vvg = (const float*)d_in[18];
  const float* W_sv1 = (const float*)d_in[19];
  const float* W_vs1 = (const float*)d_in[20];
  const float* fc_W1 = (const float*)d_in[21];
  const float* fc_b1 = (const float*)d_in[22];
  const float* fc_W2 = (const float*)d_in[23];
  const float* fc_b2 = (const float*)d_in[24];
  const float* fc_W3 = (const float*)d_in[25];
  const float* fc_b3 = (const float*)d_in[26];
  const float* ln_w_s = (const float*)d_in[27];
  const float* ln_b_s = (const float*)d_in[28];
  const float* ln_w_v = (const float*)d_in[29];

  char* ws = (char*)d_ws;
  short* blob   = (short*)(ws + OFF_BLOB);
  short* s_lin  = (short*)(ws + OFF_SLIN);
  short* v_linT = (short*)(ws + OFF_VLIN);
  float* acc_s  = (float*)(ws + OFF_ACCS);
  float* acc_v  = (float*)(ws + OFF_ACCV);
  float* grp    = (float*)(ws + OFF_GRP);
  float* ns_buf = (float*)(ws + OFF_NS);
  float* nv_buf = (float*)(ws + OFF_NV);

  // zero segment-sum accumulators + group stats in ONE memset (contiguous)
  hipMemsetAsync(acc_s, 0, 6400256, stream);

  k_prep<<<108, 64, 0, stream>>>(W_ss0, W_ssg, W_sv1, W_vv0, W_vvg, W_vs1,
                                 fc_W1, fc_W2, fc_W3, blob);
  k_node<<<NN, 64, 0, stream>>>(node_fea, lp_Ws, lp_bs, lp_Wv, s_lin, v_linT);
  k_edge<<<512, 512, 0, stream>>>(edge_sh, edge_fea, ele, eidx, blob, s_lin, v_linT,
                                  fc_b1, fc_b2, fc_b3, acc_s, acc_v);
  k_post1<<<NN, 64, 0, stream>>>(node_fea, one_hot, batch, pp_Ws, pp_bs, pp_Wv,
                                 sc_Ws, sc_Wv, acc_s, acc_v, ns_buf, nv_buf, grp);
  k_post3<<<NN, 64, 0, stream>>>(node_fea, batch, ln_w_s, ln_b_s, ln_w_v,
                                 ns_buf, nv_buf, grp, (float*)d_out);
}

// Round 4
// 1119.400 us; speedup vs baseline: 1.1453x; 1.1453x over previous
//
#include <hip/hip_runtime.h>
#include <math.h>

// ---------------- problem constants ----------------
#define NN 10000          // nodes
#define NE 320000         // edges
#define NGR 16            // graphs
#define NGROUPS16 (NE/16) // 20000 edge groups of 16

// workspace offsets (bytes) -- all 16B aligned
#define OFF_BLOB  0u          // 108 frags * 1KB bf16 weight blob
#define OFF_SLIN  110592u     // N*64 bf16
#define OFF_VLIN  1390592u    // N*96 bf16 (layout [n][d*32+w])
#define OFF_ACCS  3310592u    // N*64 f32 (segment sum zs)
#define OFF_ACCV  5870592u    // N*96 f32 (segment sum zv, layout [n][d*32+w])
#define OFF_GRP   9710592u    // 64 f32 group accumulators
#define OFF_CNT   9710848u    // 10000 ints (histogram) -- memset'd with acc region
#define OFF_ROW   9750848u    // 10001 ints row offsets
#define OFF_CUR   9790864u    // 10000 ints scatter cursors
#define OFF_ELIST 9830864u    // 320000 ints sorted edge ids
#define OFF_NS    11110864u   // N*64 f32 scratch
#define OFF_NV    13670864u   // N*96 f32 scratch

typedef __attribute__((ext_vector_type(8))) short s8v;   // 8 bf16 = one MFMA A/B frag
typedef __attribute__((ext_vector_type(4))) float f4v;   // MFMA C/D frag

__device__ __forceinline__ short f2bf(float f) {
  union { float f; unsigned u; } v; v.f = f;
  unsigned r = v.u + 0x7fffu + ((v.u >> 16) & 1u);
  return (short)(r >> 16);
}
__device__ __forceinline__ float bf2f(short s) {
  union { float f; unsigned u; } v; v.u = ((unsigned)(unsigned short)s) << 16;
  return v.f;
}
__device__ __forceinline__ f4v mfma16(s8v a, s8v b, f4v c) {
  return __builtin_amdgcn_mfma_f32_16x16x32_bf16(a, b, c, 0, 0, 0);
}
__device__ __forceinline__ s8v ldB(const short* blob, int f, int lane) {
  return *(const s8v*)(blob + f*512 + lane*8);
}
__device__ __forceinline__ s8v cvt8v(f4v a, f4v b) {
  s8v r;
  r[0]=f2bf(a[0]); r[1]=f2bf(a[1]); r[2]=f2bf(a[2]); r[3]=f2bf(a[3]);
  r[4]=f2bf(b[0]); r[5]=f2bf(b[1]); r[6]=f2bf(b[2]); r[7]=f2bf(b[3]);
  return r;
}
__device__ __forceinline__ float wave_sum(float v) {
  #pragma unroll
  for (int off = 32; off > 0; off >>= 1) v += __shfl_xor(v, off);
  return v;
}

// ---------------- CSR build: sort edges by target node ----------------
__global__ void k_hist(const int* eidx, int* cnt) {
  int e = blockIdx.x*256 + threadIdx.x;
  if (e < NE) atomicAdd(&cnt[eidx[e]], 1);
}
__global__ void k_scan(const int* cnt, int* row, int* cur) {
  __shared__ int part[1024];
  int t = threadIdx.x;
  int s = 0, loc[10];
  if (t < 1000) {
    #pragma unroll
    for (int k = 0; k < 10; ++k) { loc[k] = cnt[t*10 + k]; s += loc[k]; }
  }
  part[t] = s;
  __syncthreads();
  for (int off = 1; off < 1024; off <<= 1) {
    int v = (t >= off) ? part[t - off] : 0;
    __syncthreads();
    part[t] += v;
    __syncthreads();
  }
  if (t < 1000) {
    int base = part[t] - s;  // exclusive prefix
    #pragma unroll
    for (int k = 0; k < 10; ++k) { row[t*10+k] = base; cur[t*10+k] = base; base += loc[k]; }
  }
  if (t == 0) row[10000] = NE;
}
__global__ void k_scatter(const int* eidx, int* cur, int* elist) {
  int e = blockIdx.x*256 + threadIdx.x;
  if (e < NE) { int p = atomicAdd(&cur[eidx[e]], 1); elist[p] = e; }
}

// ---------------- K0: pack weights into bf16 B-fragment blob ----------------
__global__ void k_prep(const float* W_ss0, const float* W_ssg, const float* W_sv1,
                       const float* W_vv0, const float* W_vvg, const float* W_vs1,
                       const float* fc_W1, const float* fc_W2, const float* fc_W3,
                       short* blob) {
  const float inv_fan = 0.05892556509887896f; // 1/sqrt(288)
  int f = blockIdx.x, l = threadIdx.x;
  int q = l >> 4, nl = l & 15;
  s8v out;
  #pragma unroll
  for (int j = 0; j < 8; ++j) {
    float w;
    if (f < 48) {
      int nt = f / 6, kt = f % 6, k = kt*32 + q*8 + j, c = nt*16 + nl;
      w = (c < 64 ? W_ss0[k*64 + c] : (c < 96 ? W_ssg[k*32 + (c-64)] : W_sv1[k*32 + (c-96)])) * inv_fan;
    } else if (f < 66) {
      int fl = f - 48, nt = fl / 3, kt = fl % 3, k = kt*32 + q*8 + j, c = nt*16 + nl;
      w = (c < 64 ? W_vv0[k*64 + c] : W_vvg[k*32 + (c-64)]) * inv_fan;
    } else if (f < 72) {
      int fl = f - 66, nt = fl / 3, kt = fl % 3, k = kt*32 + q*8 + j, c = nt*16 + nl;
      w = W_vs1[k*32 + c] * inv_fan;
    } else if (f < 88) {
      int fl = f - 72, nt = fl / 4, kt = fl % 4, k = kt*32 + q*8 + j, c = nt*16 + nl;
      w = fc_W1[k*64 + c];
    } else if (f < 96) {
      int fl = f - 88, nt = fl / 2, kt = fl % 2, k = kt*32 + q*8 + j, c = nt*16 + nl;
      w = fc_W2[k*64 + c];
    } else {
      int fl = f - 96, nt = fl / 2, kt = fl % 2, k = kt*32 + q*8 + j, c = nt*16 + nl;
      w = fc_W3[k*96 + c];
    }
    out[j] = f2bf(w);
  }
  *(s8v*)(blob + f*512 + l*8) = out;
}

// ---------------- K1: per-node linear pre-transform (lp), store bf16 ----------------
__global__ void k_node(const float* node_fea, const float* lp_Ws, const float* lp_bs,
                       const float* lp_Wv, short* s_lin, short* v_linT) {
  int n = blockIdx.x, lane = threadIdx.x;
  const float* nf = node_fea + n*160;
  float a = 0.f;
  for (int u = 0; u < 64; ++u) a += nf[u] * lp_Ws[u*64 + lane];
  s_lin[n*64 + lane] = f2bf(a * 0.125f + lp_bs[lane]);
  for (int o = lane; o < 96; o += 64) {
    int d = o >> 5, w = o & 31;
    float acc = 0.f;
    for (int u = 0; u < 32; ++u) acc += nf[64 + u*3 + d] * lp_Wv[u*32 + w];
    v_linT[n*96 + o] = f2bf(acc * 0.17677669529663687f); // 1/sqrt(32)
  }
}

// ---------------- K2: edge kernel (MFMA), node-sorted edge order ----------------
// one wave per 16-edge group of the SORTED edge list. Epilogue does wave-level
// segmented reduction: uniform-node groups emit 10 single-line atomics instead
// of 40 scattered ones; mixed groups merge per-node runs in-lane.
__launch_bounds__(256, 2)
__global__ void k_edge(const float* edge_sh, const float* edge_fea, const float* ele,
                       const int* eidx, const int* elist, const short* blob,
                       const short* s_lin, const short* v_linT,
                       const float* fc_b1, const float* fc_b2, const float* fc_b3,
                       float* acc_s, float* acc_v) {
  __shared__ __align__(16) short hbuf[4][1024];  // per-wave 16x64 bf16 transpose buffer
  int lane = threadIdx.x & 63, wave = threadIdx.x >> 6;
  int q = lane >> 4, nl = lane & 15;
  short* hb = hbuf[wave];
  // hoist biases (constant over groups)
  float b1v[4], b2v[4], b3v[6];
  #pragma unroll
  for (int t = 0; t < 4; ++t) { b1v[t] = fc_b1[t*16 + nl]; b2v[t] = fc_b2[t*16 + nl]; }
  #pragma unroll
  for (int t = 0; t < 6; ++t) b3v[t] = fc_b3[t*16 + nl];

  // contiguous group range per wave: same-node groups stay in one wave (locality)
  int wid = blockIdx.x*4 + wave;
  int nwaves = gridDim.x * 4;
  int per = (NGROUPS16 + nwaves - 1) / nwaves;
  int gEnd = min(wid*per + per, NGROUPS16);
  for (int g = wid*per; g < gEnd; ++g) {
    int base = g * 16;
    // ======== BATCH 1: independent loads (streams + indices) ========
    int eA = elist[base + nl];
    int iA = eidx[eA], jA = eidx[NE + eA];
    f4v shE = *(const f4v*)(edge_sh + eA*4);
    const float* efp = edge_fea + eA*160;
    f4v es0 = *(const f4v*)(efp + q*8);
    f4v es1 = *(const f4v*)(efp + q*8 + 4);
    f4v es2 = *(const f4v*)(efp + 32 + q*8);
    f4v es3 = *(const f4v*)(efp + 32 + q*8 + 4);
    f4v ev[6];
    #pragma unroll
    for (int t = 0; t < 6; ++t) ev[t] = *(const f4v*)(efp + 64 + q*24 + t*4);
    f4v el[8];
    #pragma unroll
    for (int kt = 0; kt < 4; ++kt) {
      el[2*kt]   = *(const f4v*)(ele + eA*128 + kt*32 + q*8);
      el[2*kt+1] = *(const f4v*)(ele + eA*128 + kt*32 + q*8 + 4);
    }
    // ======== BATCH 2: eidx-dependent gathers (already bf16) ========
    s8v a_s1[6];
    a_s1[0] = *(const s8v*)(s_lin + iA*64 + q*8);
    a_s1[1] = *(const s8v*)(s_lin + iA*64 + 32 + q*8);
    a_s1[2] = *(const s8v*)(s_lin + jA*64 + q*8);
    a_s1[3] = *(const s8v*)(s_lin + jA*64 + 32 + q*8);
    s8v a_v[3][3];
    #pragma unroll
    for (int d = 0; d < 3; ++d) {
      a_v[d][0] = *(const s8v*)(v_linT + iA*96 + d*32 + q*8);
      a_v[d][1] = *(const s8v*)(v_linT + jA*96 + d*32 + q*8);
    }

    // ======== COMPUTE (consume in issue order; gathers consumed last) ========
    s8v a_e[4];
    #pragma unroll
    for (int kt = 0; kt < 4; ++kt) a_e[kt] = cvt8v(el[2*kt], el[2*kt+1]);
    #pragma unroll
    for (int nt = 0; nt < 4; ++nt) {
      f4v acc = {0.f, 0.f, 0.f, 0.f};
      #pragma unroll
      for (int kt = 0; kt < 4; ++kt) acc = mfma16(a_e[kt], ldB(blob, 72 + nt*4 + kt, lane), acc);
      #pragma unroll
      for (int r = 0; r < 4; ++r) {
        float x = acc[r] + b1v[nt];
        x = x / (1.f + __expf(-x));
        hb[(q*4 + r)*64 + nt*16 + nl] = f2bf(x);
      }
    }
    s8v ha0 = *(const s8v*)(hb + nl*64 + q*8);
    s8v ha1 = *(const s8v*)(hb + nl*64 + 32 + q*8);
    #pragma unroll
    for (int nt = 0; nt < 4; ++nt) {
      f4v acc = {0.f, 0.f, 0.f, 0.f};
      acc = mfma16(ha0, ldB(blob, 88 + nt*2 + 0, lane), acc);
      acc = mfma16(ha1, ldB(blob, 88 + nt*2 + 1, lane), acc);
      #pragma unroll
      for (int r = 0; r < 4; ++r) {
        float x = acc[r] + b2v[nt];
        x = x / (1.f + __expf(-x));
        hb[(q*4 + r)*64 + nt*16 + nl] = f2bf(x);
      }
    }
    s8v g0 = *(const s8v*)(hb + nl*64 + q*8);
    s8v g1 = *(const s8v*)(hb + nl*64 + 32 + q*8);
    f4v Wfc[6];
    #pragma unroll
    for (int nt = 0; nt < 6; ++nt) {
      f4v acc = {0.f, 0.f, 0.f, 0.f};
      acc = mfma16(g0, ldB(blob, 96 + nt*2 + 0, lane), acc);
      acc = mfma16(g1, ldB(blob, 96 + nt*2 + 1, lane), acc);
      #pragma unroll
      for (int r = 0; r < 4; ++r) acc[r] += b3v[nt];
      Wfc[nt] = acc;
    }
    a_s1[4] = cvt8v(es0, es1);
    a_s1[5] = cvt8v(es2, es3);
    #pragma unroll
    for (int d = 0; d < 3; ++d)
      #pragma unroll
      for (int j = 0; j < 8; ++j) {
        int idx = j*3 + d;
        a_v[d][2][j] = f2bf(ev[idx >> 2][idx & 3]);
      }
    float s10 = shE[1] * 0.5773502691896258f;
    float s11 = shE[2] * 0.5773502691896258f;
    float s12 = shE[3] * 0.5773502691896258f;
    s8v a_dd[3];
    #pragma unroll
    for (int kt = 0; kt < 3; ++kt)
      #pragma unroll
      for (int j = 0; j < 8; ++j)
        a_dd[kt][j] = f2bf(bf2f(a_v[0][kt][j])*s10 + bf2f(a_v[1][kt][j])*s11 + bf2f(a_v[2][kt][j])*s12);
    f4v P2[6];
    #pragma unroll
    for (int nt = 0; nt < 6; ++nt) {
      f4v acc = {0.f, 0.f, 0.f, 0.f};
      #pragma unroll
      for (int kt = 0; kt < 3; ++kt) acc = mfma16(a_dd[kt], ldB(blob, 48 + nt*3 + kt, lane), acc);
      P2[nt] = acc;
    }
    f4v P3[3][2];
    #pragma unroll
    for (int d = 0; d < 3; ++d)
      #pragma unroll
      for (int nt = 0; nt < 2; ++nt) P3[d][nt] = (f4v){0.f, 0.f, 0.f, 0.f};
    #pragma unroll
    for (int nt = 0; nt < 2; ++nt)
      #pragma unroll
      for (int kt = 0; kt < 3; ++kt) {
        s8v b = ldB(blob, 66 + nt*3 + kt, lane);
        #pragma unroll
        for (int d = 0; d < 3; ++d) P3[d][nt] = mfma16(a_v[d][kt], b, P3[d][nt]);
      }
    // ---- epilogue per-edge scalars via intra-wave shuffle
    int nodeI[4]; float sh0v[4], sh1v[4][3];
    #pragma unroll
    for (int r = 0; r < 4; ++r) {
      int src = q*4 + r;
      nodeI[r] = __shfl(iA, src);
      sh0v[r] = __shfl(shE[0], src);
      sh1v[r][0] = __shfl(shE[1], src);
      sh1v[r][1] = __shfl(shE[2], src);
      sh1v[r][2] = __shfl(shE[3], src);
    }
    int nFirst = __shfl(iA, 0), nLast = __shfl(iA, 15);
    bool uni = (nFirst == nLast);   // wave-uniform branch
    // ---- zs tiles nt=0..3 (P1 on demand, fused epilogue)
    #pragma unroll
    for (int nt = 0; nt < 4; ++nt) {
      f4v acc = {0.f, 0.f, 0.f, 0.f};
      #pragma unroll
      for (int kt = 0; kt < 6; ++kt) acc = mfma16(a_s1[kt], ldB(blob, nt*6 + kt, lane), acc);
      float val[4];
      #pragma unroll
      for (int r = 0; r < 4; ++r) {
        float zs = acc[r] * sh0v[r] + P2[nt][r];
        val[r] = zs / (1.f + __expf(-zs)) * Wfc[nt][r];
      }
      if (uni) {
        float v = val[0] + val[1] + val[2] + val[3];
        v += __shfl_xor(v, 16); v += __shfl_xor(v, 32);
        if (q == 0) unsafeAtomicAdd(acc_s + nFirst*64 + nt*16 + nl, v);
      } else {
        float a = val[0];
        #pragma unroll
        for (int r = 1; r < 4; ++r) {
          if (nodeI[r] == nodeI[r-1]) a += val[r];
          else { unsafeAtomicAdd(acc_s + nodeI[r-1]*64 + nt*16 + nl, a); a = val[r]; }
        }
        unsafeAtomicAdd(acc_s + nodeI[3]*64 + nt*16 + nl, a);
      }
    }
    // ---- zv tiles
    #pragma unroll
    for (int tg = 0; tg < 2; ++tg) {
      f4v accg = {0.f, 0.f, 0.f, 0.f};
      f4v accv = {0.f, 0.f, 0.f, 0.f};
      #pragma unroll
      for (int kt = 0; kt < 6; ++kt) {
        accg = mfma16(a_s1[kt], ldB(blob, (4+tg)*6 + kt, lane), accg);
        accv = mfma16(a_s1[kt], ldB(blob, (6+tg)*6 + kt, lane), accv);
      }
      float gval[3][4];
      #pragma unroll
      for (int r = 0; r < 4; ++r) {
        float zg = accg[r] * sh0v[r] + P2[4+tg][r];
        float gw = Wfc[4+tg][r] / (1.f + __expf(-zg));
        float sv = accv[r];
        #pragma unroll
        for (int d = 0; d < 3; ++d)
          gval[d][r] = (sv * sh1v[r][d] + P3[d][tg][r] * sh0v[r]) * gw;
      }
      #pragma unroll
      for (int d = 0; d < 3; ++d) {
        if (uni) {
          float v = gval[d][0] + gval[d][1] + gval[d][2] + gval[d][3];
          v += __shfl_xor(v, 16); v += __shfl_xor(v, 32);
          if (q == 0) unsafeAtomicAdd(acc_v + nFirst*96 + d*32 + tg*16 + nl, v);
        } else {
          float a = gval[d][0];
          #pragma unroll
          for (int r = 1; r < 4; ++r) {
            if (nodeI[r] == nodeI[r-1]) a += gval[d][r];
            else { unsafeAtomicAdd(acc_v + nodeI[r-1]*96 + d*32 + tg*16 + nl, a); a = gval[d][r]; }
          }
          unsafeAtomicAdd(acc_v + nodeI[3]*96 + d*32 + tg*16 + nl, a);
        }
      }
    }
  }
}

// ---------------- K3: per-node pp-transform + sc, group stats (single pass) ----------------
__global__ void k_post1(const float* node_fea, const float* one_hot, const int* batch,
                        const float* pp_Ws, const float* pp_bs, const float* pp_Wv,
                        const float* sc_Ws, const float* sc_Wv,
                        const float* acc_s, const float* acc_v,
                        float* ns_buf, float* nv_buf, float* grp) {
  int n = blockIdx.x, lane = threadIdx.x, g = batch[n];
  const float* oh = one_hot + n*4;
  int sp = oh[1] > 0.5f ? 1 : (oh[2] > 0.5f ? 2 : (oh[3] > 0.5f ? 3 : 0));
  const float* nf = node_fea + n*160;
  float a = 0.f, sc = 0.f;
  for (int u = 0; u < 64; ++u) {
    a  += acc_s[n*64 + u] * pp_Ws[u*64 + lane];
    sc += nf[u] * sc_Ws[(u*4 + sp)*64 + lane];
  }
  float ns = a * 0.125f + pp_bs[lane] + sc * 0.0625f;  // /8, /16
  ns_buf[n*64 + lane] = ns;
  float ssum = wave_sum(ns);
  float s2sum = wave_sum(ns * ns);
  float v2 = 0.f;
  for (int o = lane; o < 96; o += 64) {
    int w = o / 3, i = o - w*3;
    float av = 0.f, scv = 0.f;
    for (int u = 0; u < 32; ++u) {
      av  += acc_v[n*96 + i*32 + u] * pp_Wv[u*32 + w];   // acc_v layout [n][d*32+u]
      scv += nf[64 + u*3 + i] * sc_Wv[(u*4 + sp)*32 + w];
    }
    float nv = av * 0.17677669529663687f + scv * 0.08838834764831844f; // /sqrt32, /sqrt128
    nv_buf[n*96 + o] = nv;
    v2 += nv * nv;
  }
  float vsum = wave_sum(v2);
  if (lane == 0) {
    unsafeAtomicAdd(grp + g, ssum * (1.f/64.f));
    unsafeAtomicAdd(grp + 16 + g, 1.f);
    unsafeAtomicAdd(grp + 32 + g, vsum * (1.f/96.f));
    unsafeAtomicAdd(grp + 48 + g, s2sum * (1.f/64.f));
  }
}

// ---------------- K5: center + normalize + residual + output ----------------
__global__ void k_post3(const float* node_fea, const int* batch,
                        const float* ln_w_s, const float* ln_b_s, const float* ln_w_v,
                        const float* ns_buf, const float* nv_buf, const float* grp,
                        float* out) {
  int n = blockIdx.x, lane = threadIdx.x, g = batch[n];
  float cnt = fmaxf(grp[16 + g], 1.f);
  float mu = grp[g] / cnt;
  float var_s = fmaxf(grp[48 + g] / cnt - mu*mu, 0.f);
  float inv_s = rsqrtf(var_s + 1e-5f);
  float inv_v = rsqrtf(grp[32 + g] / cnt + 1e-5f);
  const float* nf = node_fea + n*160;
  out[n*160 + lane] = nf[lane] + (ns_buf[n*64 + lane] - mu) * inv_s * ln_w_s[lane] + ln_b_s[lane];
  for (int o = lane; o < 96; o += 64) {
    int w = o / 3;
    out[n*160 + 64 + o] = nf[64 + o] + nv_buf[n*96 + o] * inv_v * ln_w_v[w];
  }
}

extern "C" void kernel_launch(void* const* d_in, const int* in_sizes, int n_in,
                              void* d_out, int out_size, void* d_ws, size_t ws_size,
                              hipStream_t stream) {
  const float* node_fea = (const float*)d_in[0];
  const float* one_hot  = (const float*)d_in[1];
  const float* edge_sh  = (const float*)d_in[2];
  const float* edge_fea = (const float*)d_in[3];
  const float* ele      = (const float*)d_in[4];
  const int*   eidx     = (const int*)d_in[5];
  const int*   batch    = (const int*)d_in[6];
  const float* lp_Ws = (const float*)d_in[7];
  const float* lp_bs = (const float*)d_in[8];
  const float* lp_Wv = (const float*)d_in[9];
  const float* pp_Ws = (const float*)d_in[10];
  const float* pp_bs = (const float*)d_in[11];
  const float* pp_Wv = (const float*)d_in[12];
  const float* sc_Ws = (const float*)d_in[13];
  const float* sc_Wv = (const float*)d_in[14];
  const float* W_ss0 = (const float*)d_in[15];
  const float* W_vv0 = (const float*)d_in[16];
  const float* W_ssg = (const float*)d_in[17];
  const float* W_vvg = (const float*)d_in[18];
  const float* W_sv1 = (const float*)d_in[19];
  const float* W_vs1 = (const float*)d_in[20];
  const float* fc_W1 = (const float*)d_in[21];
  const float* fc_b1 = (const float*)d_in[22];
  const float* fc_W2 = (const float*)d_in[23];
  const float* fc_b2 = (const float*)d_in[24];
  const float* fc_W3 = (const float*)d_in[25];
  const float* fc_b3 = (const float*)d_in[26];
  const float* ln_w_s = (const float*)d_in[27];
  const float* ln_b_s = (const float*)d_in[28];
  const float* ln_w_v = (const float*)d_in[29];

  char* ws = (char*)d_ws;
  short* blob   = (short*)(ws + OFF_BLOB);
  short* s_lin  = (short*)(ws + OFF_SLIN);
  short* v_linT = (short*)(ws + OFF_VLIN);
  float* acc_s  = (float*)(ws + OFF_ACCS);
  float* acc_v  = (float*)(ws + OFF_ACCV);
  float* grp    = (float*)(ws + OFF_GRP);
  int*   cnt    = (int*)(ws + OFF_CNT);
  int*   row    = (int*)(ws + OFF_ROW);
  int*   cur    = (int*)(ws + OFF_CUR);
  int*   elist  = (int*)(ws + OFF_ELIST);
  float* ns_buf = (float*)(ws + OFF_NS);
  float* nv_buf = (float*)(ws + OFF_NV);

  // zero acc_s + acc_v + grp + cnt in ONE memset (contiguous region)
  hipMemsetAsync(acc_s, 0, 6440256, stream);

  k_hist<<<1250, 256, 0, stream>>>(eidx, cnt);
  k_scan<<<1, 1024, 0, stream>>>(cnt, row, cur);
  k_scatter<<<1250, 256, 0, stream>>>(eidx, cur, elist);
  k_prep<<<108, 64, 0, stream>>>(W_ss0, W_ssg, W_sv1, W_vv0, W_vvg, W_vs1,
                                 fc_W1, fc_W2, fc_W3, blob);
  k_node<<<NN, 64, 0, stream>>>(node_fea, lp_Ws, lp_bs, lp_Wv, s_lin, v_linT);
  k_edge<<<512, 256, 0, stream>>>(edge_sh, edge_fea, ele, eidx, elist, blob, s_lin, v_linT,
                                  fc_b1, fc_b2, fc_b3, acc_s, acc_v);
  k_post1<<<NN, 64, 0, stream>>>(node_fea, one_hot, batch, pp_Ws, pp_bs, pp_Wv,
                                 sc_Ws, sc_Wv, acc_s, acc_v, ns_buf, nv_buf, grp);
  k_post3<<<NN, 64, 0, stream>>>(node_fea, batch, ln_w_s, ln_b_s, ln_w_v,
                                 ns_buf, nv_buf, grp, (float*)d_out);
}

// Round 6
// 823.784 us; speedup vs baseline: 1.5562x; 1.3589x over previous
//
#include <hip/hip_runtime.h>
#include <math.h>

// ---------------- problem constants ----------------
#define NN 10000          // nodes
#define NE 320000         // edges
#define NGR 16            // graphs
#define NGROUPS16 (NE/16) // 20000 edge groups of 16

// workspace offsets (bytes) -- all 16B aligned
#define OFF_BLOB  0u          // 108 frags * 1KB bf16 weight blob
#define OFF_SLIN  110592u     // N*64 bf16
#define OFF_VLIN  1390592u    // N*96 bf16 (layout [n][d*32+w])
#define OFF_ACCS  3310592u    // N*64 f32 (segment sum zs)
#define OFF_ACCV  5870592u    // N*96 f32 (segment sum zv, layout [n][d*32+w])
#define OFF_GRP   9710592u    // 64 f32 group accumulators
#define OFF_CNT   9710848u    // 10000 ints (histogram) -- memset'd with acc region
#define OFF_ROW   9750848u    // 10001 ints row offsets
#define OFF_CUR   9790864u    // 10000 ints scatter cursors
#define OFF_ELIST 9830864u    // 320000 ints sorted edge ids
#define OFF_NS    11110864u   // N*64 f32 scratch
#define OFF_NV    13670864u   // N*96 f32 scratch

typedef __attribute__((ext_vector_type(8))) short s8v;   // 8 bf16 = one MFMA A/B frag
typedef __attribute__((ext_vector_type(4))) float f4v;   // MFMA C/D frag

__device__ __forceinline__ short f2bf(float f) {
  union { float f; unsigned u; } v; v.f = f;
  unsigned r = v.u + 0x7fffu + ((v.u >> 16) & 1u);
  return (short)(r >> 16);
}
__device__ __forceinline__ float bf2f(short s) {
  union { float f; unsigned u; } v; v.u = ((unsigned)(unsigned short)s) << 16;
  return v.f;
}
__device__ __forceinline__ f4v mfma16(s8v a, s8v b, f4v c) {
  return __builtin_amdgcn_mfma_f32_16x16x32_bf16(a, b, c, 0, 0, 0);
}
__device__ __forceinline__ s8v cvt8v(f4v a, f4v b) {
  s8v r;
  r[0]=f2bf(a[0]); r[1]=f2bf(a[1]); r[2]=f2bf(a[2]); r[3]=f2bf(a[3]);
  r[4]=f2bf(b[0]); r[5]=f2bf(b[1]); r[6]=f2bf(b[2]); r[7]=f2bf(b[3]);
  return r;
}
__device__ __forceinline__ float wave_sum(float v) {
  #pragma unroll
  for (int off = 32; off > 0; off >>= 1) v += __shfl_xor(v, off);
  return v;
}

// ---------------- CSR build: sort edges by target node ----------------
__global__ void k_hist(const int* eidx, int* cnt) {
  int e = blockIdx.x*256 + threadIdx.x;
  if (e < NE) atomicAdd(&cnt[eidx[e]], 1);
}
__global__ void k_scan(const int* cnt, int* row, int* cur) {
  __shared__ int part[1024];
  int t = threadIdx.x;
  int s = 0, loc[10];
  if (t < 1000) {
    #pragma unroll
    for (int k = 0; k < 10; ++k) { loc[k] = cnt[t*10 + k]; s += loc[k]; }
  }
  part[t] = s;
  __syncthreads();
  for (int off = 1; off < 1024; off <<= 1) {
    int v = (t >= off) ? part[t - off] : 0;
    __syncthreads();
    part[t] += v;
    __syncthreads();
  }
  if (t < 1000) {
    int base = part[t] - s;  // exclusive prefix
    #pragma unroll
    for (int k = 0; k < 10; ++k) { row[t*10+k] = base; cur[t*10+k] = base; base += loc[k]; }
  }
  if (t == 0) row[10000] = NE;
}
__global__ void k_scatter(const int* eidx, int* cur, int* elist) {
  int e = blockIdx.x*256 + threadIdx.x;
  if (e < NE) { int p = atomicAdd(&cur[eidx[e]], 1); elist[p] = e; }
}

// ---------------- K0: pack weights into bf16 B-fragment blob ----------------
__global__ void k_prep(const float* W_ss0, const float* W_ssg, const float* W_sv1,
                       const float* W_vv0, const float* W_vvg, const float* W_vs1,
                       const float* fc_W1, const float* fc_W2, const float* fc_W3,
                       short* blob) {
  const float inv_fan = 0.05892556509887896f; // 1/sqrt(288)
  int f = blockIdx.x, l = threadIdx.x;
  int q = l >> 4, nl = l & 15;
  s8v out;
  #pragma unroll
  for (int j = 0; j < 8; ++j) {
    float w;
    if (f < 48) {
      int nt = f / 6, kt = f % 6, k = kt*32 + q*8 + j, c = nt*16 + nl;
      w = (c < 64 ? W_ss0[k*64 + c] : (c < 96 ? W_ssg[k*32 + (c-64)] : W_sv1[k*32 + (c-96)])) * inv_fan;
    } else if (f < 66) {
      int fl = f - 48, nt = fl / 3, kt = fl % 3, k = kt*32 + q*8 + j, c = nt*16 + nl;
      w = (c < 64 ? W_vv0[k*64 + c] : W_vvg[k*32 + (c-64)]) * inv_fan;
    } else if (f < 72) {
      int fl = f - 66, nt = fl / 3, kt = fl % 3, k = kt*32 + q*8 + j, c = nt*16 + nl;
      w = W_vs1[k*32 + c] * inv_fan;
    } else if (f < 88) {
      int fl = f - 72, nt = fl / 4, kt = fl % 4, k = kt*32 + q*8 + j, c = nt*16 + nl;
      w = fc_W1[k*64 + c];
    } else if (f < 96) {
      int fl = f - 88, nt = fl / 2, kt = fl % 2, k = kt*32 + q*8 + j, c = nt*16 + nl;
      w = fc_W2[k*64 + c];
    } else {
      int fl = f - 96, nt = fl / 2, kt = fl % 2, k = kt*32 + q*8 + j, c = nt*16 + nl;
      w = fc_W3[k*96 + c];
    }
    out[j] = f2bf(w);
  }
  *(s8v*)(blob + f*512 + l*8) = out;
}

// ---------------- K1: per-node linear pre-transform (lp), store bf16 ----------------
__global__ void k_node(const float* node_fea, const float* lp_Ws, const float* lp_bs,
                       const float* lp_Wv, short* s_lin, short* v_linT) {
  int n = blockIdx.x, lane = threadIdx.x;
  const float* nf = node_fea + n*160;
  float a = 0.f;
  for (int u = 0; u < 64; ++u) a += nf[u] * lp_Ws[u*64 + lane];
  s_lin[n*64 + lane] = f2bf(a * 0.125f + lp_bs[lane]);
  for (int o = lane; o < 96; o += 64) {
    int d = o >> 5, w = o & 31;
    float acc = 0.f;
    for (int u = 0; u < 32; ++u) acc += nf[64 + u*3 + d] * lp_Wv[u*32 + w];
    v_linT[n*96 + o] = f2bf(acc * 0.17677669529663687f); // 1/sqrt(32)
  }
}

// ---------------- K2: edge kernel (MFMA), node-sorted, blob in LDS ----------------
// 512-thread blocks (8 waves), one wave per 16-edge group. The full 108KB
// B-fragment blob is staged in LDS once per block: all 108 per-group ldB
// global loads become ds_read_b128 (conflict-free: lane reads contiguous 16B)
// -> removes the dominant serialized-latency chain. Next-group indices
// (elist/eidx/edge_sh) prefetched before the epilogue so the dependent gather
// chain overlaps current compute + atomic retirement.
// grid=256: exactly 1 block/CU (LDS-limited anyway) -> blob staged once per CU.
#define LDB(f) (*(const s8v*)(lblob + (f)*512 + lane*8))
__launch_bounds__(512, 2)
__global__ void k_edge(const float* edge_sh, const float* edge_fea, const float* ele,
                       const int* eidx, const int* elist, const short* blob,
                       const short* s_lin, const short* v_linT,
                       const float* fc_b1, const float* fc_b2, const float* fc_b3,
                       float* acc_s, float* acc_v) {
  __shared__ __align__(16) short lblob[55296];   // 108 frags * 512 shorts = 108KB
  __shared__ __align__(16) short hbuf[8][1024];  // per-wave 16x64 bf16 transpose buffer
  int lane = threadIdx.x & 63, wave = threadIdx.x >> 6;
  int q = lane >> 4, nl = lane & 15;
  short* hb = hbuf[wave];

  // ---- stage blob into LDS (once per block), 16B per lane per iter
  for (int c = threadIdx.x; c < 6912; c += 512)
    *(s8v*)(lblob + c*8) = *(const s8v*)(blob + c*8);
  __syncthreads();

  // hoist biases (constant over groups)
  float b1v[4], b2v[4], b3v[6];
  #pragma unroll
  for (int t = 0; t < 4; ++t) { b1v[t] = fc_b1[t*16 + nl]; b2v[t] = fc_b2[t*16 + nl]; }
  #pragma unroll
  for (int t = 0; t < 6; ++t) b3v[t] = fc_b3[t*16 + nl];

  // contiguous group range per wave: same-node groups stay in one wave (locality)
  int wid = blockIdx.x*8 + wave;
  int nwaves = gridDim.x * 8;
  int per = (NGROUPS16 + nwaves - 1) / nwaves;
  int gBeg = wid*per;
  int gEnd = min(gBeg + per, NGROUPS16);
  if (gBeg >= gEnd) return;

  // pre-loop index load for first group
  int eA = elist[gBeg*16 + nl];
  int iA = eidx[eA], jA = eidx[NE + eA];
  f4v shE = *(const f4v*)(edge_sh + eA*4);

  for (int g = gBeg; g < gEnd; ++g) {
    // ======== BATCH 1: stream loads for current group ========
    const float* efp = edge_fea + eA*160;
    f4v es0 = *(const f4v*)(efp + q*8);
    f4v es1 = *(const f4v*)(efp + q*8 + 4);
    f4v es2 = *(const f4v*)(efp + 32 + q*8);
    f4v es3 = *(const f4v*)(efp + 32 + q*8 + 4);
    f4v ev[6];
    #pragma unroll
    for (int t = 0; t < 6; ++t) ev[t] = *(const f4v*)(efp + 64 + q*24 + t*4);
    f4v el[8];
    #pragma unroll
    for (int kt = 0; kt < 4; ++kt) {
      el[2*kt]   = *(const f4v*)(ele + eA*128 + kt*32 + q*8);
      el[2*kt+1] = *(const f4v*)(ele + eA*128 + kt*32 + q*8 + 4);
    }
    // ======== BATCH 2: node gathers (already bf16) ========
    s8v a_s1[6];
    a_s1[0] = *(const s8v*)(s_lin + iA*64 + q*8);
    a_s1[1] = *(const s8v*)(s_lin + iA*64 + 32 + q*8);
    a_s1[2] = *(const s8v*)(s_lin + jA*64 + q*8);
    a_s1[3] = *(const s8v*)(s_lin + jA*64 + 32 + q*8);
    s8v a_v[3][3];
    #pragma unroll
    for (int d = 0; d < 3; ++d) {
      a_v[d][0] = *(const s8v*)(v_linT + iA*96 + d*32 + q*8);
      a_v[d][1] = *(const s8v*)(v_linT + jA*96 + d*32 + q*8);
    }
    // ======== prefetch next group's indices (overlaps compute below) ========
    int eA_n = eA, iA_n = iA, jA_n = jA; f4v shE_n = shE;
    if (g + 1 < gEnd) {
      eA_n = elist[(g+1)*16 + nl];
      iA_n = eidx[eA_n]; jA_n = eidx[NE + eA_n];
      shE_n = *(const f4v*)(edge_sh + eA_n*4);
    }

    // ======== COMPUTE (consume in issue order; gathers consumed last) ========
    s8v a_e[4];
    #pragma unroll
    for (int kt = 0; kt < 4; ++kt) a_e[kt] = cvt8v(el[2*kt], el[2*kt+1]);
    #pragma unroll
    for (int nt = 0; nt < 4; ++nt) {
      f4v acc = {0.f, 0.f, 0.f, 0.f};
      #pragma unroll
      for (int kt = 0; kt < 4; ++kt) acc = mfma16(a_e[kt], LDB(72 + nt*4 + kt), acc);
      #pragma unroll
      for (int r = 0; r < 4; ++r) {
        float x = acc[r] + b1v[nt];
        x = x / (1.f + __expf(-x));
        hb[(q*4 + r)*64 + nt*16 + nl] = f2bf(x);
      }
    }
    s8v ha0 = *(const s8v*)(hb + nl*64 + q*8);
    s8v ha1 = *(const s8v*)(hb + nl*64 + 32 + q*8);
    #pragma unroll
    for (int nt = 0; nt < 4; ++nt) {
      f4v acc = {0.f, 0.f, 0.f, 0.f};
      acc = mfma16(ha0, LDB(88 + nt*2 + 0), acc);
      acc = mfma16(ha1, LDB(88 + nt*2 + 1), acc);
      #pragma unroll
      for (int r = 0; r < 4; ++r) {
        float x = acc[r] + b2v[nt];
        x = x / (1.f + __expf(-x));
        hb[(q*4 + r)*64 + nt*16 + nl] = f2bf(x);
      }
    }
    s8v g0 = *(const s8v*)(hb + nl*64 + q*8);
    s8v g1 = *(const s8v*)(hb + nl*64 + 32 + q*8);
    f4v Wfc[6];
    #pragma unroll
    for (int nt = 0; nt < 6; ++nt) {
      f4v acc = {0.f, 0.f, 0.f, 0.f};
      acc = mfma16(g0, LDB(96 + nt*2 + 0), acc);
      acc = mfma16(g1, LDB(96 + nt*2 + 1), acc);
      #pragma unroll
      for (int r = 0; r < 4; ++r) acc[r] += b3v[nt];
      Wfc[nt] = acc;
    }
    a_s1[4] = cvt8v(es0, es1);
    a_s1[5] = cvt8v(es2, es3);
    #pragma unroll
    for (int d = 0; d < 3; ++d)
      #pragma unroll
      for (int j = 0; j < 8; ++j) {
        int idx = j*3 + d;
        a_v[d][2][j] = f2bf(ev[idx >> 2][idx & 3]);
      }
    float s10 = shE[1] * 0.5773502691896258f;
    float s11 = shE[2] * 0.5773502691896258f;
    float s12 = shE[3] * 0.5773502691896258f;
    s8v a_dd[3];
    #pragma unroll
    for (int kt = 0; kt < 3; ++kt)
      #pragma unroll
      for (int j = 0; j < 8; ++j)
        a_dd[kt][j] = f2bf(bf2f(a_v[0][kt][j])*s10 + bf2f(a_v[1][kt][j])*s11 + bf2f(a_v[2][kt][j])*s12);
    f4v P2[6];
    #pragma unroll
    for (int nt = 0; nt < 6; ++nt) {
      f4v acc = {0.f, 0.f, 0.f, 0.f};
      #pragma unroll
      for (int kt = 0; kt < 3; ++kt) acc = mfma16(a_dd[kt], LDB(48 + nt*3 + kt), acc);
      P2[nt] = acc;
    }
    f4v P3[3][2];
    #pragma unroll
    for (int d = 0; d < 3; ++d)
      #pragma unroll
      for (int nt = 0; nt < 2; ++nt) P3[d][nt] = (f4v){0.f, 0.f, 0.f, 0.f};
    #pragma unroll
    for (int nt = 0; nt < 2; ++nt)
      #pragma unroll
      for (int kt = 0; kt < 3; ++kt) {
        s8v b = LDB(66 + nt*3 + kt);
        #pragma unroll
        for (int d = 0; d < 3; ++d) P3[d][nt] = mfma16(a_v[d][kt], b, P3[d][nt]);
      }
    // ---- epilogue per-edge scalars via intra-wave shuffle (uses CURRENT iA/shE)
    int nodeI[4]; float sh0v[4], sh1v[4][3];
    #pragma unroll
    for (int r = 0; r < 4; ++r) {
      int src = q*4 + r;
      nodeI[r] = __shfl(iA, src);
      sh0v[r] = __shfl(shE[0], src);
      sh1v[r][0] = __shfl(shE[1], src);
      sh1v[r][1] = __shfl(shE[2], src);
      sh1v[r][2] = __shfl(shE[3], src);
    }
    int nFirst = __shfl(iA, 0), nLast = __shfl(iA, 15);
    bool uni = (nFirst == nLast);   // wave-uniform branch
    // ---- zs tiles nt=0..3 (P1 on demand, fused epilogue)
    #pragma unroll
    for (int nt = 0; nt < 4; ++nt) {
      f4v acc = {0.f, 0.f, 0.f, 0.f};
      #pragma unroll
      for (int kt = 0; kt < 6; ++kt) acc = mfma16(a_s1[kt], LDB(nt*6 + kt), acc);
      float val[4];
      #pragma unroll
      for (int r = 0; r < 4; ++r) {
        float zs = acc[r] * sh0v[r] + P2[nt][r];
        val[r] = zs / (1.f + __expf(-zs)) * Wfc[nt][r];
      }
      if (uni) {
        float v = val[0] + val[1] + val[2] + val[3];
        v += __shfl_xor(v, 16); v += __shfl_xor(v, 32);
        if (q == 0) unsafeAtomicAdd(acc_s + nFirst*64 + nt*16 + nl, v);
      } else {
        float a = val[0];
        #pragma unroll
        for (int r = 1; r < 4; ++r) {
          if (nodeI[r] == nodeI[r-1]) a += val[r];
          else { unsafeAtomicAdd(acc_s + nodeI[r-1]*64 + nt*16 + nl, a); a = val[r]; }
        }
        unsafeAtomicAdd(acc_s + nodeI[3]*64 + nt*16 + nl, a);
      }
    }
    // ---- zv tiles
    #pragma unroll
    for (int tg = 0; tg < 2; ++tg) {
      f4v accg = {0.f, 0.f, 0.f, 0.f};
      f4v accv = {0.f, 0.f, 0.f, 0.f};
      #pragma unroll
      for (int kt = 0; kt < 6; ++kt) {
        accg = mfma16(a_s1[kt], LDB((4+tg)*6 + kt), accg);
        accv = mfma16(a_s1[kt], LDB((6+tg)*6 + kt), accv);
      }
      float gval[3][4];
      #pragma unroll
      for (int r = 0; r < 4; ++r) {
        float zg = accg[r] * sh0v[r] + P2[4+tg][r];
        float gw = Wfc[4+tg][r] / (1.f + __expf(-zg));
        float sv = accv[r];
        #pragma unroll
        for (int d = 0; d < 3; ++d)
          gval[d][r] = (sv * sh1v[r][d] + P3[d][tg][r] * sh0v[r]) * gw;
      }
      #pragma unroll
      for (int d = 0; d < 3; ++d) {
        if (uni) {
          float v = gval[d][0] + gval[d][1] + gval[d][2] + gval[d][3];
          v += __shfl_xor(v, 16); v += __shfl_xor(v, 32);
          if (q == 0) unsafeAtomicAdd(acc_v + nFirst*96 + d*32 + tg*16 + nl, v);
        } else {
          float a = gval[d][0];
          #pragma unroll
          for (int r = 1; r < 4; ++r) {
            if (nodeI[r] == nodeI[r-1]) a += gval[d][r];
            else { unsafeAtomicAdd(acc_v + nodeI[r-1]*96 + d*32 + tg*16 + nl, a); a = gval[d][r]; }
          }
          unsafeAtomicAdd(acc_v + nodeI[3]*96 + d*32 + tg*16 + nl, a);
        }
      }
    }
    // rotate prefetched indices
    eA = eA_n; iA = iA_n; jA = jA_n; shE = shE_n;
  }
}

// ---------------- K3: per-node pp-transform + sc, group stats (single pass) ----------------
__global__ void k_post1(const float* node_fea, const float* one_hot, const int* batch,
                        const float* pp_Ws, const float* pp_bs, const float* pp_Wv,
                        const float* sc_Ws, const float* sc_Wv,
                        const float* acc_s, const float* acc_v,
                        float* ns_buf, float* nv_buf, float* grp) {
  int n = blockIdx.x, lane = threadIdx.x, g = batch[n];
  const float* oh = one_hot + n*4;
  int sp = oh[1] > 0.5f ? 1 : (oh[2] > 0.5f ? 2 : (oh[3] > 0.5f ? 3 : 0));
  const float* nf = node_fea + n*160;
  float a = 0.f, sc = 0.f;
  for (int u = 0; u < 64; ++u) {
    a  += acc_s[n*64 + u] * pp_Ws[u*64 + lane];
    sc += nf[u] * sc_Ws[(u*4 + sp)*64 + lane];
  }
  float ns = a * 0.125f + pp_bs[lane] + sc * 0.0625f;  // /8, /16
  ns_buf[n*64 + lane] = ns;
  float ssum = wave_sum(ns);
  float s2sum = wave_sum(ns * ns);
  float v2 = 0.f;
  for (int o = lane; o < 96; o += 64) {
    int w = o / 3, i = o - w*3;
    float av = 0.f, scv = 0.f;
    for (int u = 0; u < 32; ++u) {
      av  += acc_v[n*96 + i*32 + u] * pp_Wv[u*32 + w];   // acc_v layout [n][d*32+u]
      scv += nf[64 + u*3 + i] * sc_Wv[(u*4 + sp)*32 + w];
    }
    float nv = av * 0.17677669529663687f + scv * 0.08838834764831844f; // /sqrt32, /sqrt128
    nv_buf[n*96 + o] = nv;
    v2 += nv * nv;
  }
  float vsum = wave_sum(v2);
  if (lane == 0) {
    unsafeAtomicAdd(grp + g, ssum * (1.f/64.f));
    unsafeAtomicAdd(grp + 16 + g, 1.f);
    unsafeAtomicAdd(grp + 32 + g, vsum * (1.f/96.f));
    unsafeAtomicAdd(grp + 48 + g, s2sum * (1.f/64.f));
  }
}

// ---------------- K5: center + normalize + residual + output ----------------
__global__ void k_post3(const float* node_fea, const int* batch,
                        const float* ln_w_s, const float* ln_b_s, const float* ln_w_v,
                        const float* ns_buf, const float* nv_buf, const float* grp,
                        float* out) {
  int n = blockIdx.x, lane = threadIdx.x, g = batch[n];
  float cnt = fmaxf(grp[16 + g], 1.f);
  float mu = grp[g] / cnt;
  float var_s = fmaxf(grp[48 + g] / cnt - mu*mu, 0.f);
  float inv_s = rsqrtf(var_s + 1e-5f);
  float inv_v = rsqrtf(grp[32 + g] / cnt + 1e-5f);
  const float* nf = node_fea + n*160;
  out[n*160 + lane] = nf[lane] + (ns_buf[n*64 + lane] - mu) * inv_s * ln_w_s[lane] + ln_b_s[lane];
  for (int o = lane; o < 96; o += 64) {
    int w = o / 3;
    out[n*160 + 64 + o] = nf[64 + o] + nv_buf[n*96 + o] * inv_v * ln_w_v[w];
  }
}

extern "C" void kernel_launch(void* const* d_in, const int* in_sizes, int n_in,
                              void* d_out, int out_size, void* d_ws, size_t ws_size,
                              hipStream_t stream) {
  const float* node_fea = (const float*)d_in[0];
  const float* one_hot  = (const float*)d_in[1];
  const float* edge_sh  = (const float*)d_in[2];
  const float* edge_fea = (const float*)d_in[3];
  const float* ele      = (const float*)d_in[4];
  const int*   eidx     = (const int*)d_in[5];
  const int*   batch    = (const int*)d_in[6];
  const float* lp_Ws = (const float*)d_in[7];
  const float* lp_bs = (const float*)d_in[8];
  const float* lp_Wv = (const float*)d_in[9];
  const float* pp_Ws = (const float*)d_in[10];
  const float* pp_bs = (const float*)d_in[11];
  const float* pp_Wv = (const float*)d_in[12];
  const float* sc_Ws = (const float*)d_in[13];
  const float* sc_Wv = (const float*)d_in[14];
  const float* W_ss0 = (const float*)d_in[15];
  const float* W_vv0 = (const float*)d_in[16];
  const float* W_ssg = (const float*)d_in[17];
  const float* W_vvg = (const float*)d_in[18];
  const float* W_sv1 = (const float*)d_in[19];
  const float* W_vs1 = (const float*)d_in[20];
  const float* fc_W1 = (const float*)d_in[21];
  const float* fc_b1 = (const float*)d_in[22];
  const float* fc_W2 = (const float*)d_in[23];
  const float* fc_b2 = (const float*)d_in[24];
  const float* fc_W3 = (const float*)d_in[25];
  const float* fc_b3 = (const float*)d_in[26];
  const float* ln_w_s = (const float*)d_in[27];
  const float* ln_b_s = (const float*)d_in[28];
  const float* ln_w_v = (const float*)d_in[29];

  char* ws = (char*)d_ws;
  short* blob   = (short*)(ws + OFF_BLOB);
  short* s_lin  = (short*)(ws + OFF_SLIN);
  short* v_linT = (short*)(ws + OFF_VLIN);
  float* acc_s  = (float*)(ws + OFF_ACCS);
  float* acc_v  = (float*)(ws + OFF_ACCV);
  float* grp    = (float*)(ws + OFF_GRP);
  int*   cnt    = (int*)(ws + OFF_CNT);
  int*   row    = (int*)(ws + OFF_ROW);
  int*   cur    = (int*)(ws + OFF_CUR);
  int*   elist  = (int*)(ws + OFF_ELIST);
  float* ns_buf = (float*)(ws + OFF_NS);
  float* nv_buf = (float*)(ws + OFF_NV);

  // zero acc_s + acc_v + grp + cnt in ONE memset (contiguous region)
  hipMemsetAsync(acc_s, 0, 6440256, stream);

  k_hist<<<1250, 256, 0, stream>>>(eidx, cnt);
  k_scan<<<1, 1024, 0, stream>>>(cnt, row, cur);
  k_scatter<<<1250, 256, 0, stream>>>(eidx, cur, elist);
  k_prep<<<108, 64, 0, stream>>>(W_ss0, W_ssg, W_sv1, W_vv0, W_vvg, W_vs1,
                                 fc_W1, fc_W2, fc_W3, blob);
  k_node<<<NN, 64, 0, stream>>>(node_fea, lp_Ws, lp_bs, lp_Wv, s_lin, v_linT);
  k_edge<<<256, 512, 0, stream>>>(edge_sh, edge_fea, ele, eidx, elist, blob, s_lin, v_linT,
                                  fc_b1, fc_b2, fc_b3, acc_s, acc_v);
  k_post1<<<NN, 64, 0, stream>>>(node_fea, one_hot, batch, pp_Ws, pp_bs, pp_Wv,
                                 sc_Ws, sc_Wv, acc_s, acc_v, ns_buf, nv_buf, grp);
  k_post3<<<NN, 64, 0, stream>>>(node_fea, batch, ln_w_s, ln_b_s, ln_w_v,
                                 ns_buf, nv_buf, grp, (float*)d_out);
}